// Round 9
// baseline (5337.299 us; speedup 1.0000x reference)
//
#include <hip/hip_runtime.h>
#include <hip/hip_bf16.h>
#include <math.h>

typedef _Float16 hf;

__device__ __forceinline__ hf f2h(float x){ return (hf)x; }

#define NHEADS 8
#define CAP 128

// s: LDS row; w: global f32 weight row (16B-aligned); n % 4 == 0
__device__ __forceinline__ float dotf(const float* __restrict__ s, const float* __restrict__ w, int n){
  float acc = 0.f;
  const float4* w4 = (const float4*)w;
  #pragma unroll 4
  for (int j = 0; j < (n >> 2); ++j){
    float4 wv = w4[j];
    acc += s[4*j]*wv.x + s[4*j+1]*wv.y + s[4*j+2]*wv.z + s[4*j+3]*wv.w;
  }
  return acc;
}

// sentinel fill (f32)
__global__ void fill_const(float* __restrict__ p, float v, int n){
  int i = blockIdx.x*blockDim.x + threadIdx.x;
  if (i < n) p[i] = v;
}

// ---------------- CSR build ----------------
__global__ void edge_hist(const int* __restrict__ ei, int E, int* __restrict__ deg){
  int e = blockIdx.x*blockDim.x + threadIdx.x;
  if (e >= E) return;
  atomicAdd(&deg[ei[E + e]], 1);
}

__global__ __launch_bounds__(1024) void scan_kernel(const int* __restrict__ deg,
      int* __restrict__ rowptr, int* __restrict__ cursor, int Nn, int E){
  __shared__ int sums[1024];
  int t = threadIdx.x;
  int chunk = (Nn + 1023) >> 10;
  int b0 = t*chunk;
  int s = 0;
  for (int i=0;i<chunk;i++){ int idx=b0+i; if (idx<Nn) s += deg[idx]; }
  sums[t] = s;
  __syncthreads();
  for (int off=1; off<1024; off<<=1){
    int v = (t>=off) ? sums[t-off] : 0;
    __syncthreads();
    sums[t] += v;
    __syncthreads();
  }
  int run = (t==0) ? 0 : sums[t-1];
  for (int i=0;i<chunk;i++){
    int idx=b0+i;
    if (idx<Nn){ rowptr[idx]=run; cursor[idx]=run; run += deg[idx]; }
  }
  if (t==1023) rowptr[Nn] = E;
}

__global__ void edge_scatter(const int* __restrict__ ei, const int* __restrict__ ety, int E,
                             int* __restrict__ cursor, unsigned* __restrict__ srcet){
  int e = blockIdx.x*blockDim.x + threadIdx.x;
  if (e >= E) return;
  int pos = atomicAdd(&cursor[ei[E + e]], 1);
  srcet[pos] = ((unsigned)ety[e] << 16) | (unsigned)ei[e];
}

// ---------------- naive QKV: one block per node ----------------
__global__ __launch_bounds__(128) void qkv_naive(const float* __restrict__ nf, const float* __restrict__ qe,
    const float* __restrict__ Wq, const float* __restrict__ bq,
    const float* __restrict__ Wk, const float* __restrict__ bk,
    const float* __restrict__ Wv, const float* __restrict__ bv,
    hf* __restrict__ qkv){
  int n = blockIdx.x, t = threadIdx.x;
  __shared__ float nqr[256];
  nqr[t]       = nf[(long)n*128 + t];
  nqr[128 + t] = qe[t];
  __syncthreads();
  float qv = dotf(nqr, Wq + (long)t*256, 256) + bq[t];
  float kv = dotf(nqr, Wk + (long)t*256, 256) + bk[t];
  float vv = dotf(nqr, Wv + (long)t*128, 128) + bv[t];
  qkv[(long)n*384 + t]       = f2h(qv);
  qkv[(long)n*384 + 128 + t] = f2h(kv);
  qkv[(long)n*384 + 256 + t] = f2h(vv);
}

// ---------------- per-node attention softmax + aggregation ----------------
// thread t = h*16+d; no max-subtract: seg_max = max(0, seg_max) >= 0 and scores O(1):
// ref denom = sum exp(s-m)+1e-8 vs ours sum exp(s)+1e-8 -> negligible difference.
__global__ __launch_bounds__(128) void attn_agg(const hf* __restrict__ qkv, const float* __restrict__ rel,
     const int* __restrict__ rowptr, const unsigned* __restrict__ srcet,
     hf* __restrict__ agg){
  int n = blockIdx.x, t = threadIdx.x;
  __shared__ float sbuf[CAP * NHEADS];
  const int h = t >> 4;
  float qv = (float)qkv[(long)n*384 + t];
  int beg = rowptr[n], end = rowptr[n+1];
  float denom = 0.f;
  for (int i = beg; i < end; ++i){
    unsigned se = srcet[i];
    int src = se & 0xFFFF;
    int et  = se >> 16;
    float kb = (float)qkv[(long)src*384 + 128 + t] + rel[(long)et*128 + t];
    float p = qv * kb;
    p += __shfl_xor(p, 1); p += __shfl_xor(p, 2);
    p += __shfl_xor(p, 4); p += __shfl_xor(p, 8);
    float es = expf(p * 0.25f);
    int il = i - beg;
    if (il < CAP && (t & 15) == 0) sbuf[il*NHEADS + h] = es;
    denom += es;
  }
  float inv = 1.f / (denom + 1e-8f);
  __syncthreads();
  float acc = 0.f;
  for (int i = beg; i < end; ++i){
    unsigned se = srcet[i];
    int src = se & 0xFFFF;
    float es;
    int il = i - beg;
    if (il < CAP) es = sbuf[il*NHEADS + h];
    else {
      int et = se >> 16;
      float kb = (float)qkv[(long)src*384 + 128 + t] + rel[(long)et*128 + t];
      float p = qv * kb;
      p += __shfl_xor(p, 1); p += __shfl_xor(p, 2);
      p += __shfl_xor(p, 4); p += __shfl_xor(p, 8);
      es = expf(p * 0.25f);
    }
    acc += es * (float)qkv[(long)src*384 + 256 + t];
  }
  agg[(long)n*128 + t] = f2h(acc * inv);
}

// ---------------- Wo matvec + residual + LN1 fused ----------------
__global__ __launch_bounds__(128) void wo_ln(const hf* __restrict__ agg, const float* __restrict__ nf,
    const float* __restrict__ Wo, const float* __restrict__ bo,
    const float* __restrict__ g, const float* __restrict__ b, hf* __restrict__ xout){
  int n = blockIdx.x, t = threadIdx.x;
  __shared__ float ar[128];
  ar[t] = (float)agg[(long)n*128 + t];
  __syncthreads();
  float ao = dotf(ar, Wo + (long)t*128, 128) + bo[t];
  float y = nf[(long)n*128 + t] + ao;
  float s = y, s2 = y*y;
  #pragma unroll
  for (int off=32; off>0; off>>=1){ s += __shfl_xor(s, off); s2 += __shfl_xor(s2, off); }
  __shared__ float ps[4];
  if ((t & 63) == 0){ ps[(t>>6)*2] = s; ps[(t>>6)*2+1] = s2; }
  __syncthreads();
  float tot = ps[0] + ps[2], tot2 = ps[1] + ps[3];
  float mu = tot * (1.f/128.f);
  float var = tot2 * (1.f/128.f) - mu*mu;
  float rs = rsqrtf(var + 1e-5f);
  xout[(long)n*128 + t] = f2h((y - mu)*rs*g[t] + b[t]);
}

// ---------------- FFN + residual + LN2 fused (f32 output) ----------------
__global__ __launch_bounds__(128) void ffn_ln(const hf* __restrict__ X,
    const float* __restrict__ W1, const float* __restrict__ b1,
    const float* __restrict__ W2, const float* __restrict__ b2,
    const float* __restrict__ g, const float* __restrict__ bb, float* __restrict__ out){
  int n = blockIdx.x, t = threadIdx.x;
  __shared__ float xr[128];
  __shared__ float hs[512];
  xr[t] = (float)X[(long)n*128 + t];
  __syncthreads();
  #pragma unroll
  for (int k=0;k<4;k++){
    int j = k*128 + t;
    float v = dotf(xr, W1 + (long)j*128, 128) + b1[j];
    v = 0.5f * v * (1.f + erff(v * 0.70710678118f));  // exact GELU
    hs[j] = v;
  }
  __syncthreads();
  float fo = dotf(hs, W2 + (long)t*512, 512) + b2[t];
  float y = xr[t] + fo;
  float s = y, s2 = y*y;
  #pragma unroll
  for (int off=32; off>0; off>>=1){ s += __shfl_xor(s, off); s2 += __shfl_xor(s2, off); }
  __shared__ float ps[4];
  if ((t & 63) == 0){ ps[(t>>6)*2] = s; ps[(t>>6)*2+1] = s2; }
  __syncthreads();
  float tot = ps[0] + ps[2], tot2 = ps[1] + ps[3];
  float mu = tot * (1.f/128.f);
  float var = tot2 * (1.f/128.f) - mu*mu;
  float rs = rsqrtf(var + 1e-5f);
  out[(long)n*128 + t] = (y - mu)*rs*g[t] + bb[t];
}

// ---------------- relational interaction layer (R=100, f32 output) ----------------
__global__ __launch_bounds__(128) void rel_layer(const float* __restrict__ rel, const float* __restrict__ relW,
    const float* __restrict__ relb, const float* __restrict__ Wc, const float* __restrict__ bc,
    const float* __restrict__ gn, const float* __restrict__ bn, float* __restrict__ out){
  int rr = blockIdx.x, t = threadIdx.x;
  __shared__ float rrow[128];
  __shared__ float comb[512];
  rrow[t] = rel[(long)rr*128 + t];
  __syncthreads();
  #pragma unroll
  for (int k=0;k<4;k++){
    // t_out[r,k,o] = sum_h rel[r,h] * relW[k,o,h];  relW flat: (k*128+o)*128+h
    comb[k*128 + t] = dotf(rrow, relW + ((long)(k*128) + t)*128, 128) + relb[k*128 + t];
  }
  __syncthreads();
  float c2 = dotf(comb, Wc + (long)t*512, 512) + bc[t];
  float y = rrow[t] + c2;
  float s = y, s2 = y*y;
  #pragma unroll
  for (int off=32; off>0; off>>=1){ s += __shfl_xor(s, off); s2 += __shfl_xor(s2, off); }
  __shared__ float ps[4];
  if ((t & 63) == 0){ ps[(t>>6)*2] = s; ps[(t>>6)*2+1] = s2; }
  __syncthreads();
  float tot = ps[0] + ps[2], tot2 = ps[1] + ps[3];
  float mu = tot * (1.f/128.f);
  float var = tot2 * (1.f/128.f) - mu*mu;
  float rs = rsqrtf(var + 1e-5f);
  out[(long)rr*128 + t] = (y - mu)*rs*gn[t] + bn[t];
}

extern "C" void kernel_launch(void* const* d_in, const int* in_sizes, int n_in,
                              void* d_out, int out_size, void* d_ws, size_t ws_size,
                              hipStream_t stream){
  // ---- host-side input signature verification (dict-order contract) ----
  const int H = 128;
  auto S = [&](int i){ return in_sizes[i]; };
  bool ok = (n_in == 27);
  if (ok){
    ok = ok && S(1)==H && (S(0)%H)==0 && S(2)==2*S(3) && (S(4)%H)==0;
    ok = ok && S(5)==2*H*H && S(6)==H && S(7)==2*H*H && S(8)==H;
    ok = ok && S(9)==H*H  && S(10)==H && S(11)==H*H  && S(12)==H;
    ok = ok && S(13)==H && S(14)==H && S(15)==H && S(16)==H;
    ok = ok && S(17)==4*H*H && S(18)==4*H && S(19)==4*H*H && S(20)==H;
    ok = ok && S(21)==4*H*H && S(22)==4*H && S(23)==4*H*H && S(24)==H;
    ok = ok && S(25)==H && S(26)==H;
    ok = ok && out_size == S(0) + S(4);
  }
  if (!ok){   // sentinel ~100: input order/sizes differ from dict-order assumption
    fill_const<<<(out_size + 255)/256, 256, 0, stream>>>((float*)d_out, 100.0f, out_size);
    return;
  }

  const float* nf   = (const float*)d_in[0];
  const float* qe   = (const float*)d_in[1];
  const int*   ei   = (const int*)  d_in[2];
  const int*   ety  = (const int*)  d_in[3];
  const float* rel  = (const float*)d_in[4];
  const float* Wq   = (const float*)d_in[5];
  const float* bq   = (const float*)d_in[6];
  const float* Wk   = (const float*)d_in[7];
  const float* bk   = (const float*)d_in[8];
  const float* Wv   = (const float*)d_in[9];
  const float* bv   = (const float*)d_in[10];
  const float* Wo   = (const float*)d_in[11];
  const float* bo   = (const float*)d_in[12];
  const float* n1g  = (const float*)d_in[13];
  const float* n1b  = (const float*)d_in[14];
  const float* n2g  = (const float*)d_in[15];
  const float* n2b  = (const float*)d_in[16];
  const float* W1   = (const float*)d_in[17];
  const float* b1   = (const float*)d_in[18];
  const float* W2   = (const float*)d_in[19];
  const float* b2v  = (const float*)d_in[20];
  const float* relW = (const float*)d_in[21];
  const float* relb = (const float*)d_in[22];
  const float* Wc   = (const float*)d_in[23];
  const float* bc   = (const float*)d_in[24];
  const float* rng  = (const float*)d_in[25];
  const float* rnb  = (const float*)d_in[26];

  const int N = in_sizes[0] / 128;
  const int E = in_sizes[2] / 2;
  const int R = in_sizes[4] / 128;

  char* ws = (char*)d_ws;
  size_t off = 0;
  auto alloc = [&](size_t bytes)->char*{
    char* p = ws + off; off = (off + bytes + 255) & ~(size_t)255; return p;
  };
  hf*       qkv    = (hf*)      alloc((size_t)N * 768);   // [N,384] q|k|v, f16
  hf*       aggp   = (hf*)      alloc((size_t)N * 256);
  hf*       xl     = (hf*)      alloc((size_t)N * 256);
  int*      deg    = (int*)     alloc((size_t)N * 4);
  int*      rowptr = (int*)     alloc((size_t)(N+1) * 4);
  int*      cursor = (int*)     alloc((size_t)N * 4);
  unsigned* srcet  = (unsigned*)alloc((size_t)E * 4);

  if (off > ws_size){   // sentinel ~50: workspace too small
    fill_const<<<(out_size + 255)/256, 256, 0, stream>>>((float*)d_out, 50.0f, out_size);
    return;
  }

  float* outx = (float*)d_out;
  float* outr = (float*)d_out + (size_t)N*128;

  hipMemsetAsync(deg, 0, (size_t)N*4, stream);
  edge_hist<<<(E + 255)/256, 256, 0, stream>>>(ei, E, deg);
  scan_kernel<<<1, 1024, 0, stream>>>(deg, rowptr, cursor, N, E);
  edge_scatter<<<(E + 255)/256, 256, 0, stream>>>(ei, ety, E, cursor, srcet);

  qkv_naive<<<N, 128, 0, stream>>>(nf, qe, Wq, bq, Wk, bk, Wv, bv, qkv);
  attn_agg<<<N, 128, 0, stream>>>(qkv, rel, rowptr, srcet, aggp);
  wo_ln<<<N, 128, 0, stream>>>(aggp, nf, Wo, bo, n1g, n1b, xl);
  ffn_ln<<<N, 128, 0, stream>>>(xl, W1, b1, W2, b2v, n2g, n2b, outx);
  rel_layer<<<R, 128, 0, stream>>>(rel, relW, relb, Wc, bc, rng, rnb, outr);
}

// Round 10
// 749.378 us; speedup vs baseline: 7.1223x; 7.1223x over previous
//
#include <hip/hip_runtime.h>
#include <hip/hip_bf16.h>
#include <math.h>

using bf16 = __hip_bfloat16;
typedef __attribute__((ext_vector_type(8))) short short8;
typedef __attribute__((ext_vector_type(4))) float floatx4;

__device__ __forceinline__ float b2f(bf16 x){ return __bfloat162float(x); }
__device__ __forceinline__ bf16 f2b(float x){ return __float2bfloat16(x); }
__device__ __forceinline__ short bfbits(float x){ bf16 t = __float2bfloat16(x); return *(short*)&t; }

#define NHEADS 8
#define CAP 128

__global__ void fill_const(float* __restrict__ p, float v, int n){
  int i = blockIdx.x*blockDim.x + threadIdx.x;
  if (i < n) p[i] = v;
}

// ---------------- f32 -> bf16 conversion ----------------
__global__ void conv_f2b(const float* __restrict__ src, bf16* __restrict__ dst, int n){
  int i = blockIdx.x*blockDim.x + threadIdx.x;
  if (i < n) dst[i] = f2b(src[i]);
}

// Wcat bf16 [384,256] = [Wq; Wk; Wv|0], bcat f32 [384]
__global__ void build_wcat(const float* __restrict__ Wq, const float* __restrict__ Wk,
                           const float* __restrict__ Wv, const float* __restrict__ bq,
                           const float* __restrict__ bk, const float* __restrict__ bv,
                           bf16* __restrict__ Wcat, float* __restrict__ bcat){
  int i = blockIdx.x*blockDim.x + threadIdx.x;
  if (i >= 384*256) return;
  int r = i >> 8, c = i & 255;
  float v;
  if (r < 128)       v = Wq[r*256 + c];
  else if (r < 256)  v = Wk[(r-128)*256 + c];
  else               v = (c < 128) ? Wv[(r-256)*128 + c] : 0.f;
  Wcat[i] = f2b(v);
  if (i < 384) bcat[i] = (i < 128) ? bq[i] : (i < 256 ? bk[i-128] : bv[i-256]);
}

// ---------------- CSR build ----------------
__global__ void edge_hist(const int* __restrict__ ei, int E, int* __restrict__ deg){
  int e = blockIdx.x*blockDim.x + threadIdx.x;
  if (e >= E) return;
  atomicAdd(&deg[ei[E + e]], 1);
}

__global__ __launch_bounds__(1024) void scan_kernel(const int* __restrict__ deg,
      int* __restrict__ rowptr, int* __restrict__ cursor, int Nn, int E){
  __shared__ int sums[1024];
  int t = threadIdx.x;
  int chunk = (Nn + 1023) >> 10;
  int b0 = t*chunk;
  int s = 0;
  for (int i=0;i<chunk;i++){ int idx=b0+i; if (idx<Nn) s += deg[idx]; }
  sums[t] = s;
  __syncthreads();
  for (int off=1; off<1024; off<<=1){
    int v = (t>=off) ? sums[t-off] : 0;
    __syncthreads();
    sums[t] += v;
    __syncthreads();
  }
  int run = (t==0) ? 0 : sums[t-1];
  for (int i=0;i<chunk;i++){
    int idx=b0+i;
    if (idx<Nn){ rowptr[idx]=run; cursor[idx]=run; run += deg[idx]; }
  }
  if (t==1023) rowptr[Nn] = E;
}

__global__ void edge_scatter(const int* __restrict__ ei, const int* __restrict__ ety, int E,
                             int* __restrict__ cursor, unsigned* __restrict__ srcet){
  int e = blockIdx.x*blockDim.x + threadIdx.x;
  if (e >= E) return;
  int pos = atomicAdd(&cursor[ei[E + e]], 1);
  srcet[pos] = ((unsigned)ety[e] << 16) | (unsigned)ei[e];
}

// ---------------- QKV GEMM (MFMA): [nfb|qeb] @ Wcat^T + bcat -> qkv bf16 [N,384] ----------------
__global__ __launch_bounds__(256) void gemm_qkv(const bf16* __restrict__ nfb, const bf16* __restrict__ qeb,
      const bf16* __restrict__ Wcat, const float* __restrict__ bcat, bf16* __restrict__ C, int M){
  constexpr int BK=32, LDT=40, K=256, NC=384;
  __shared__ short As[64*LDT];
  __shared__ short Bs[64*LDT];
  const int tid  = threadIdx.x;
  const int lane = tid & 63;
  const int wave = tid >> 6;
  const int wm = (wave >> 1) * 32, wn = (wave & 1) * 32;
  const long m0 = (long)blockIdx.x * 64;
  const int  n0 = blockIdx.y * 64;
  floatx4 acc00 = {0.f,0.f,0.f,0.f}, acc01 = {0.f,0.f,0.f,0.f};
  floatx4 acc10 = {0.f,0.f,0.f,0.f}, acc11 = {0.f,0.f,0.f,0.f};
  const int srow = tid >> 2, scg = (tid & 3) * 8;
  const int r = lane & 15, q = lane >> 4;
  const short* Ag = (const short*)nfb;
  const short* Qg = (const short*)qeb;
  const short* Bg = (const short*)Wcat;
  for (int k0 = 0; k0 < K; k0 += BK){
    short8 va = {0,0,0,0,0,0,0,0};
    if (k0 < 128){
      long ar = m0 + srow;
      if (ar < M) va = *(const short8*)(Ag + ar*128 + k0 + scg);
    } else {
      va = *(const short8*)(Qg + (k0-128) + scg);   // row-independent broadcast
    }
    *(short8*)(&As[srow*LDT + scg]) = va;
    *(short8*)(&Bs[srow*LDT + scg]) = *(const short8*)(Bg + (long)(n0 + srow)*K + k0 + scg);
    __syncthreads();
    short8 a0 = *(const short8*)(&As[(wm      + r)*LDT + q*8]);
    short8 a1 = *(const short8*)(&As[(wm + 16 + r)*LDT + q*8]);
    short8 b0 = *(const short8*)(&Bs[(wn      + r)*LDT + q*8]);
    short8 b1 = *(const short8*)(&Bs[(wn + 16 + r)*LDT + q*8]);
    acc00 = __builtin_amdgcn_mfma_f32_16x16x32_bf16(a0, b0, acc00, 0, 0, 0);
    acc01 = __builtin_amdgcn_mfma_f32_16x16x32_bf16(a0, b1, acc01, 0, 0, 0);
    acc10 = __builtin_amdgcn_mfma_f32_16x16x32_bf16(a1, b0, acc10, 0, 0, 0);
    acc11 = __builtin_amdgcn_mfma_f32_16x16x32_bf16(a1, b1, acc11, 0, 0, 0);
    __syncthreads();
  }
  #pragma unroll
  for (int i=0;i<2;i++)
  #pragma unroll
  for (int j=0;j<2;j++){
    floatx4 av = (i==0) ? ((j==0)?acc00:acc01) : ((j==0)?acc10:acc11);
    int col = n0 + wn + j*16 + r;
    float bsv = bcat[col];
    #pragma unroll
    for (int g=0; g<4; g++){
      long row = m0 + wm + i*16 + q*4 + g;
      if (row < M) C[row*(long)NC + col] = f2b(av[g] + bsv);
    }
  }
}

// ---------------- generic GEMM (MFMA, used for Wo): C f32 = A_bf16 @ B_bf16^T + bias ----------------
__global__ __launch_bounds__(256) void gemm_bt(const bf16* __restrict__ A, const bf16* __restrict__ B,
      const float* __restrict__ bias, float* __restrict__ C, int M, int N, int K){
  constexpr int BK=32, LDT=40;
  __shared__ short As[64*LDT];
  __shared__ short Bs[64*LDT];
  const int tid  = threadIdx.x;
  const int lane = tid & 63;
  const int wave = tid >> 6;
  const int wm = (wave >> 1) * 32, wn = (wave & 1) * 32;
  const long m0 = (long)blockIdx.x * 64;
  const int  n0 = blockIdx.y * 64;
  floatx4 acc00 = {0.f,0.f,0.f,0.f}, acc01 = {0.f,0.f,0.f,0.f};
  floatx4 acc10 = {0.f,0.f,0.f,0.f}, acc11 = {0.f,0.f,0.f,0.f};
  const int srow = tid >> 2, scg = (tid & 3) * 8;
  const int r = lane & 15, q = lane >> 4;
  const short* Ag = (const short*)A;
  const short* Bg = (const short*)B;
  for (int k0 = 0; k0 < K; k0 += BK){
    short8 va = {0,0,0,0,0,0,0,0};
    long ar = m0 + srow;
    if (ar < M) va = *(const short8*)(Ag + ar*K + k0 + scg);
    *(short8*)(&As[srow*LDT + scg]) = va;
    *(short8*)(&Bs[srow*LDT + scg]) = *(const short8*)(Bg + (long)(n0 + srow)*K + k0 + scg);
    __syncthreads();
    short8 a0 = *(const short8*)(&As[(wm      + r)*LDT + q*8]);
    short8 a1 = *(const short8*)(&As[(wm + 16 + r)*LDT + q*8]);
    short8 b0 = *(const short8*)(&Bs[(wn      + r)*LDT + q*8]);
    short8 b1 = *(const short8*)(&Bs[(wn + 16 + r)*LDT + q*8]);
    acc00 = __builtin_amdgcn_mfma_f32_16x16x32_bf16(a0, b0, acc00, 0, 0, 0);
    acc01 = __builtin_amdgcn_mfma_f32_16x16x32_bf16(a0, b1, acc01, 0, 0, 0);
    acc10 = __builtin_amdgcn_mfma_f32_16x16x32_bf16(a1, b0, acc10, 0, 0, 0);
    acc11 = __builtin_amdgcn_mfma_f32_16x16x32_bf16(a1, b1, acc11, 0, 0, 0);
    __syncthreads();
  }
  #pragma unroll
  for (int i=0;i<2;i++)
  #pragma unroll
  for (int j=0;j<2;j++){
    floatx4 av = (i==0) ? ((j==0)?acc00:acc01) : ((j==0)?acc10:acc11);
    int col = n0 + wn + j*16 + r;
    float bsv = bias[col];
    #pragma unroll
    for (int g=0; g<4; g++){
      long row = m0 + wm + i*16 + q*4 + g;
      if (row < M) C[row*(long)N + col] = av[g] + bsv;
    }
  }
}

// ---------------- per-node attention softmax + aggregation ----------------
__global__ __launch_bounds__(128) void attn_agg(const bf16* __restrict__ qkv, const float* __restrict__ rel,
     const int* __restrict__ rowptr, const unsigned* __restrict__ srcet,
     bf16* __restrict__ agg){
  int n = blockIdx.x, t = threadIdx.x;
  __shared__ float sbuf[CAP * NHEADS];
  const int h = t >> 4;
  float qv = b2f(qkv[(long)n*384 + t]);
  int beg = rowptr[n], end = rowptr[n+1];
  float denom = 0.f;
  for (int i = beg; i < end; ++i){
    unsigned se = srcet[i];
    int src = se & 0xFFFF;
    int et  = se >> 16;
    float kb = b2f(qkv[(long)src*384 + 128 + t]) + rel[(long)et*128 + t];
    float p = qv * kb;
    p += __shfl_xor(p, 1); p += __shfl_xor(p, 2);
    p += __shfl_xor(p, 4); p += __shfl_xor(p, 8);
    float es = expf(p * 0.25f);
    int il = i - beg;
    if (il < CAP && (t & 15) == 0) sbuf[il*NHEADS + h] = es;
    denom += es;
  }
  float inv = 1.f / (denom + 1e-8f);
  __syncthreads();
  float acc = 0.f;
  for (int i = beg; i < end; ++i){
    unsigned se = srcet[i];
    int src = se & 0xFFFF;
    float es;
    int il = i - beg;
    if (il < CAP) es = sbuf[il*NHEADS + h];
    else {
      int et = se >> 16;
      float kb = b2f(qkv[(long)src*384 + 128 + t]) + rel[(long)et*128 + t];
      float p = qv * kb;
      p += __shfl_xor(p, 1); p += __shfl_xor(p, 2);
      p += __shfl_xor(p, 4); p += __shfl_xor(p, 8);
      es = expf(p * 0.25f);
    }
    acc += es * b2f(qkv[(long)src*384 + 256 + t]);
  }
  agg[(long)n*128 + t] = f2b(acc * inv);
}

// ---------------- residual + LN1: x = LN(nf + attn), out bf16 ----------------
__global__ __launch_bounds__(128) void ln_add1(const float* __restrict__ nf, const float* __restrict__ attn,
     const float* __restrict__ g, const float* __restrict__ b, bf16* __restrict__ xout){
  long n = blockIdx.x; int t = threadIdx.x;
  float y = nf[n*128 + t] + attn[n*128 + t];
  float s = y, s2 = y*y;
  #pragma unroll
  for (int off=32; off>0; off>>=1){ s += __shfl_xor(s, off); s2 += __shfl_xor(s2, off); }
  __shared__ float ps[4];
  if ((t & 63) == 0){ ps[(t>>6)*2] = s; ps[(t>>6)*2+1] = s2; }
  __syncthreads();
  float tot = ps[0] + ps[2], tot2 = ps[1] + ps[3];
  float mu = tot * (1.f/128.f);
  float var = tot2 * (1.f/128.f) - mu*mu;
  float rs = rsqrtf(var + 1e-5f);
  xout[n*128 + t] = f2b((y - mu)*rs*g[t] + b[t]);
}

// ---------------- fused FFN (MFMA, h in LDS): ffo = gelu(x@W1^T+b1)@W2^T + b2, f32 out ----------------
__global__ __launch_bounds__(256) void ffn_fused(const bf16* __restrict__ X, const bf16* __restrict__ W1,
    const float* __restrict__ b1, const bf16* __restrict__ W2, const float* __restrict__ b2,
    float* __restrict__ Out, int M){
  __shared__ short Xs[64*136];
  __shared__ short Hs[64*520];
  __shared__ short Ws[64*136];     // reused for W2 chunks with stride 40
  const int tid = threadIdx.x, lane = tid & 63, wave = tid >> 6;
  const int r = lane & 15, q = lane >> 4;
  const int wm = (wave >> 1) * 32, wn = (wave & 1) * 32;
  const long m0 = (long)blockIdx.x * 64;
  const short* Xg  = (const short*)X;
  const short* W1g = (const short*)W1;
  const short* W2g = (const short*)W2;
  #pragma unroll
  for (int c=0;c<4;c++){
    int idx = c*256 + tid, row = idx >> 4, ch = (idx & 15) * 8;
    short8 v = {0,0,0,0,0,0,0,0};
    long ar = m0 + row;
    if (ar < M) v = *(const short8*)(Xg + ar*128 + ch);
    *(short8*)(&Xs[row*136 + ch]) = v;
  }
  for (int c0 = 0; c0 < 512; c0 += 64){
    #pragma unroll
    for (int c=0;c<4;c++){
      int idx = c*256 + tid, row = idx >> 4, ch = (idx & 15) * 8;
      *(short8*)(&Ws[row*136 + ch]) = *(const short8*)(W1g + (long)(c0 + row)*128 + ch);
    }
    __syncthreads();
    floatx4 h00 = {0.f,0.f,0.f,0.f}, h01 = {0.f,0.f,0.f,0.f};
    floatx4 h10 = {0.f,0.f,0.f,0.f}, h11 = {0.f,0.f,0.f,0.f};
    #pragma unroll
    for (int k0 = 0; k0 < 128; k0 += 32){
      short8 a0 = *(const short8*)(&Xs[(wm      + r)*136 + k0 + q*8]);
      short8 a1 = *(const short8*)(&Xs[(wm + 16 + r)*136 + k0 + q*8]);
      short8 b0 = *(const short8*)(&Ws[(wn      + r)*136 + k0 + q*8]);
      short8 bv = *(const short8*)(&Ws[(wn + 16 + r)*136 + k0 + q*8]);
      h00 = __builtin_amdgcn_mfma_f32_16x16x32_bf16(a0, b0, h00, 0, 0, 0);
      h01 = __builtin_amdgcn_mfma_f32_16x16x32_bf16(a0, bv, h01, 0, 0, 0);
      h10 = __builtin_amdgcn_mfma_f32_16x16x32_bf16(a1, b0, h10, 0, 0, 0);
      h11 = __builtin_amdgcn_mfma_f32_16x16x32_bf16(a1, bv, h11, 0, 0, 0);
    }
    #pragma unroll
    for (int i=0;i<2;i++)
    #pragma unroll
    for (int j=0;j<2;j++){
      floatx4 av = (i==0) ? ((j==0)?h00:h01) : ((j==0)?h10:h11);
      int col = wn + j*16 + r;
      float bb = b1[c0 + col];
      #pragma unroll
      for (int g=0; g<4; g++){
        int row = wm + i*16 + q*4 + g;
        float v = av[g] + bb;
        v = 0.5f * v * (1.f + erff(v * 0.70710678118f));   // exact GELU
        Hs[row*520 + c0 + col] = bfbits(v);
      }
    }
    __syncthreads();
  }
  const int wn2 = (wave & 1) * 64;
  floatx4 o[2][4];
  #pragma unroll
  for (int i=0;i<2;i++)
  #pragma unroll
  for (int j=0;j<4;j++) o[i][j] = (floatx4){0.f,0.f,0.f,0.f};
  for (int k0 = 0; k0 < 512; k0 += 32){
    #pragma unroll
    for (int c=0;c<2;c++){
      int idx = c*256 + tid, row = idx >> 2, ch = (idx & 3) * 8;
      *(short8*)(&Ws[row*40 + ch]) = *(const short8*)(W2g + (long)row*512 + k0 + ch);
    }
    __syncthreads();
    short8 a0 = *(const short8*)(&Hs[(wm      + r)*520 + k0 + q*8]);
    short8 a1 = *(const short8*)(&Hs[(wm + 16 + r)*520 + k0 + q*8]);
    #pragma unroll
    for (int j=0;j<4;j++){
      short8 bj = *(const short8*)(&Ws[(wn2 + j*16 + r)*40 + q*8]);
      o[0][j] = __builtin_amdgcn_mfma_f32_16x16x32_bf16(a0, bj, o[0][j], 0, 0, 0);
      o[1][j] = __builtin_amdgcn_mfma_f32_16x16x32_bf16(a1, bj, o[1][j], 0, 0, 0);
    }
    __syncthreads();
  }
  #pragma unroll
  for (int i=0;i<2;i++)
  #pragma unroll
  for (int j=0;j<4;j++){
    int col = wn2 + j*16 + r;
    float bb = b2[col];
    #pragma unroll
    for (int g=0; g<4; g++){
      long row = m0 + wm + i*16 + q*4 + g;
      if (row < M) Out[row*128 + col] = o[i][j][g] + bb;
    }
  }
}

// ---------------- residual + LN2: out = LN(x + ffo), f32 out ----------------
__global__ __launch_bounds__(128) void ln_add2(const bf16* __restrict__ X, const float* __restrict__ ffo,
     const float* __restrict__ g, const float* __restrict__ b, float* __restrict__ out){
  long n = blockIdx.x; int t = threadIdx.x;
  float y = b2f(X[n*128 + t]) + ffo[n*128 + t];
  float s = y, s2 = y*y;
  #pragma unroll
  for (int off=32; off>0; off>>=1){ s += __shfl_xor(s, off); s2 += __shfl_xor(s2, off); }
  __shared__ float ps[4];
  if ((t & 63) == 0){ ps[(t>>6)*2] = s; ps[(t>>6)*2+1] = s2; }
  __syncthreads();
  float tot = ps[0] + ps[2], tot2 = ps[1] + ps[3];
  float mu = tot * (1.f/128.f);
  float var = tot2 * (1.f/128.f) - mu*mu;
  float rs = rsqrtf(var + 1e-5f);
  out[n*128 + t] = (y - mu)*rs*g[t] + b[t];
}

// ---------------- relational interaction layer (R=100, naive f32) ----------------
__device__ __forceinline__ float dotf(const float* __restrict__ s, const float* __restrict__ w, int n){
  float acc = 0.f;
  const float4* w4 = (const float4*)w;
  #pragma unroll 4
  for (int j = 0; j < (n >> 2); ++j){
    float4 wv = w4[j];
    acc += s[4*j]*wv.x + s[4*j+1]*wv.y + s[4*j+2]*wv.z + s[4*j+3]*wv.w;
  }
  return acc;
}

__global__ __launch_bounds__(128) void rel_layer(const float* __restrict__ rel, const float* __restrict__ relW,
    const float* __restrict__ relb, const float* __restrict__ Wc, const float* __restrict__ bc,
    const float* __restrict__ gn, const float* __restrict__ bn, float* __restrict__ out){
  int rr = blockIdx.x, t = threadIdx.x;
  __shared__ float rrow[128];
  __shared__ float comb[512];
  rrow[t] = rel[(long)rr*128 + t];
  __syncthreads();
  #pragma unroll
  for (int k=0;k<4;k++){
    comb[k*128 + t] = dotf(rrow, relW + ((long)(k*128) + t)*128, 128) + relb[k*128 + t];
  }
  __syncthreads();
  float c2 = dotf(comb, Wc + (long)t*512, 512) + bc[t];
  float y = rrow[t] + c2;
  float s = y, s2 = y*y;
  #pragma unroll
  for (int off=32; off>0; off>>=1){ s += __shfl_xor(s, off); s2 += __shfl_xor(s2, off); }
  __shared__ float ps[4];
  if ((t & 63) == 0){ ps[(t>>6)*2] = s; ps[(t>>6)*2+1] = s2; }
  __syncthreads();
  float tot = ps[0] + ps[2], tot2 = ps[1] + ps[3];
  float mu = tot * (1.f/128.f);
  float var = tot2 * (1.f/128.f) - mu*mu;
  float rs = rsqrtf(var + 1e-5f);
  out[(long)rr*128 + t] = (y - mu)*rs*gn[t] + bn[t];
}

extern "C" void kernel_launch(void* const* d_in, const int* in_sizes, int n_in,
                              void* d_out, int out_size, void* d_ws, size_t ws_size,
                              hipStream_t stream){
  const int H = 128;
  auto S = [&](int i){ return in_sizes[i]; };
  bool ok = (n_in == 27);
  if (ok){
    ok = ok && S(1)==H && (S(0)%H)==0 && S(2)==2*S(3) && (S(4)%H)==0;
    ok = ok && S(5)==2*H*H && S(7)==2*H*H && S(9)==H*H && S(11)==H*H;
    ok = ok && S(17)==4*H*H && S(19)==4*H*H && S(21)==4*H*H && S(23)==4*H*H;
    ok = ok && out_size == S(0) + S(4);
  }
  if (!ok){
    fill_const<<<(out_size + 255)/256, 256, 0, stream>>>((float*)d_out, 100.0f, out_size);
    return;
  }

  const float* nf   = (const float*)d_in[0];
  const float* qe   = (const float*)d_in[1];
  const int*   ei   = (const int*)  d_in[2];
  const int*   ety  = (const int*)  d_in[3];
  const float* rel  = (const float*)d_in[4];
  const float* Wq   = (const float*)d_in[5];
  const float* bq   = (const float*)d_in[6];
  const float* Wk   = (const float*)d_in[7];
  const float* bk   = (const float*)d_in[8];
  const float* Wv   = (const float*)d_in[9];
  const float* bv   = (const float*)d_in[10];
  const float* Wo   = (const float*)d_in[11];
  const float* bo   = (const float*)d_in[12];
  const float* n1g  = (const float*)d_in[13];
  const float* n1b  = (const float*)d_in[14];
  const float* n2g  = (const float*)d_in[15];
  const float* n2b  = (const float*)d_in[16];
  const float* W1   = (const float*)d_in[17];
  const float* b1   = (const float*)d_in[18];
  const float* W2   = (const float*)d_in[19];
  const float* b2v  = (const float*)d_in[20];
  const float* relW = (const float*)d_in[21];
  const float* relb = (const float*)d_in[22];
  const float* Wc   = (const float*)d_in[23];
  const float* bc   = (const float*)d_in[24];
  const float* rng  = (const float*)d_in[25];
  const float* rnb  = (const float*)d_in[26];

  const int N = in_sizes[0] / 128;
  const int E = in_sizes[2] / 2;
  const int R = in_sizes[4] / 128;

  char* ws = (char*)d_ws;
  size_t off = 0;
  auto alloc = [&](size_t bytes)->char*{
    char* p = ws + off; off = (off + bytes + 255) & ~(size_t)255; return p;
  };
  // region NA: nfb bf16 [N,128] -> later agg bf16 [N,128] (nfb dead after gemm_qkv)
  char*     regNA  = alloc((size_t)N * 256);
  // region Q: qkv bf16 [N,384] -> later attn f32 [N,128] -> later ffo f32 [N,128]
  char*     regQ   = alloc((size_t)N * 768);
  bf16*     xlb    = (bf16*)    alloc((size_t)N * 256);   // x after LN1, bf16
  bf16*     qeb    = (bf16*)    alloc(256);
  bf16*     Wcat   = (bf16*)    alloc((size_t)384*256*2);
  float*    bcat   = (float*)   alloc(384*4);
  bf16*     Wob    = (bf16*)    alloc((size_t)128*128*2);
  bf16*     W1b    = (bf16*)    alloc((size_t)512*128*2);
  bf16*     W2b    = (bf16*)    alloc((size_t)128*512*2);
  int*      deg    = (int*)     alloc((size_t)N * 4);
  int*      rowptr = (int*)     alloc((size_t)(N+1) * 4);
  int*      cursor = (int*)     alloc((size_t)N * 4);
  unsigned* srcet  = (unsigned*)alloc((size_t)E * 4);

  if (off > ws_size){
    fill_const<<<(out_size + 255)/256, 256, 0, stream>>>((float*)d_out, 50.0f, out_size);
    return;
  }

  bf16*  nfb  = (bf16*)regNA;
  bf16*  aggp = (bf16*)regNA;     // overlays nfb (dead after gemm_qkv)
  bf16*  qkv  = (bf16*)regQ;
  float* attn = (float*)regQ;     // overlays qkv (dead after attn_agg)
  float* ffo  = (float*)regQ;     // overlays attn (dead after ln_add1)
  float* outx = (float*)d_out;
  float* outr = (float*)d_out + (size_t)N*128;

  // conversions
  conv_f2b<<<(N*128 + 255)/256, 256, 0, stream>>>(nf, nfb, N*128);
  conv_f2b<<<1, 128, 0, stream>>>(qe, qeb, 128);
  build_wcat<<<(384*256 + 255)/256, 256, 0, stream>>>(Wq, Wk, Wv, bq, bk, bv, Wcat, bcat);
  conv_f2b<<<(128*128 + 255)/256, 256, 0, stream>>>(Wo, Wob, 128*128);
  conv_f2b<<<(512*128 + 255)/256, 256, 0, stream>>>(W1, W1b, 512*128);
  conv_f2b<<<(128*512 + 255)/256, 256, 0, stream>>>(W2, W2b, 128*512);

  // CSR
  hipMemsetAsync(deg, 0, (size_t)N*4, stream);
  edge_hist<<<(E + 255)/256, 256, 0, stream>>>(ei, E, deg);
  scan_kernel<<<1, 1024, 0, stream>>>(deg, rowptr, cursor, N, E);
  edge_scatter<<<(E + 255)/256, 256, 0, stream>>>(ei, ety, E, cursor, srcet);

  // pipeline
  dim3 g1((N + 63)/64, 6);
  gemm_qkv<<<g1, 256, 0, stream>>>(nfb, qeb, Wcat, bcat, qkv, N);
  attn_agg<<<N, 128, 0, stream>>>(qkv, rel, rowptr, srcet, aggp);
  dim3 g2((N + 63)/64, 2);
  gemm_bt<<<g2, 256, 0, stream>>>(aggp, Wob, bo, attn, N, 128, 128);
  ln_add1<<<N, 128, 0, stream>>>(nf, attn, n1g, n1b, xlb);
  ffn_fused<<<(N + 63)/64, 256, 0, stream>>>(xlb, W1b, b1, W2b, b2v, ffo, N);
  ln_add2<<<N, 128, 0, stream>>>(xlb, ffo, n2g, n2b, outx);
  rel_layer<<<R, 128, 0, stream>>>(rel, relW, relb, Wc, bc, rng, rnb, outr);
}

// Round 11
// 632.839 us; speedup vs baseline: 8.4339x; 1.1842x over previous
//
#include <hip/hip_runtime.h>
#include <hip/hip_bf16.h>
#include <math.h>

using bf16 = __hip_bfloat16;
typedef __attribute__((ext_vector_type(8))) short short8;
typedef __attribute__((ext_vector_type(4))) float floatx4;

__device__ __forceinline__ float b2f(bf16 x){ return __bfloat162float(x); }
__device__ __forceinline__ bf16 f2b(float x){ return __float2bfloat16(x); }
__device__ __forceinline__ short bfbits(float x){ bf16 t = __float2bfloat16(x); return *(short*)&t; }
__device__ __forceinline__ float lo2f(unsigned u){ return __uint_as_float(u << 16); }
__device__ __forceinline__ float hi2f(unsigned u){ return __uint_as_float(u & 0xFFFF0000u); }

__global__ void fill_const(float* __restrict__ p, float v, int n){
  int i = blockIdx.x*blockDim.x + threadIdx.x;
  if (i < n) p[i] = v;
}

__global__ void conv_f2b(const float* __restrict__ src, bf16* __restrict__ dst, int n){
  int i = blockIdx.x*blockDim.x + threadIdx.x;
  if (i < n) dst[i] = f2b(src[i]);
}

// Wcat bf16 [384,256] = [Wq; Wk; Wv|0], bcat f32 [384]
__global__ void build_wcat(const float* __restrict__ Wq, const float* __restrict__ Wk,
                           const float* __restrict__ Wv, const float* __restrict__ bq,
                           const float* __restrict__ bk, const float* __restrict__ bv,
                           bf16* __restrict__ Wcat, float* __restrict__ bcat){
  int i = blockIdx.x*blockDim.x + threadIdx.x;
  if (i >= 384*256) return;
  int r = i >> 8, c = i & 255;
  float v;
  if (r < 128)       v = Wq[r*256 + c];
  else if (r < 256)  v = Wk[(r-128)*256 + c];
  else               v = (c < 128) ? Wv[(r-256)*128 + c] : 0.f;
  Wcat[i] = f2b(v);
  if (i < 384) bcat[i] = (i < 128) ? bq[i] : (i < 256 ? bk[i-128] : bv[i-256]);
}

// ---------------- CSR build ----------------
__global__ void edge_hist(const int* __restrict__ ei, int E, int* __restrict__ deg){
  int e = blockIdx.x*blockDim.x + threadIdx.x;
  if (e >= E) return;
  atomicAdd(&deg[ei[E + e]], 1);
}

__global__ __launch_bounds__(1024) void scan_kernel(const int* __restrict__ deg,
      int* __restrict__ rowptr, int* __restrict__ cursor, int Nn, int E){
  __shared__ int sums[1024];
  int t = threadIdx.x;
  int chunk = (Nn + 1023) >> 10;
  int b0 = t*chunk;
  int s = 0;
  for (int i=0;i<chunk;i++){ int idx=b0+i; if (idx<Nn) s += deg[idx]; }
  sums[t] = s;
  __syncthreads();
  for (int off=1; off<1024; off<<=1){
    int v = (t>=off) ? sums[t-off] : 0;
    __syncthreads();
    sums[t] += v;
    __syncthreads();
  }
  int run = (t==0) ? 0 : sums[t-1];
  for (int i=0;i<chunk;i++){
    int idx=b0+i;
    if (idx<Nn){ rowptr[idx]=run; cursor[idx]=run; run += deg[idx]; }
  }
  if (t==1023) rowptr[Nn] = E;
}

__global__ void edge_scatter(const int* __restrict__ ei, const int* __restrict__ ety, int E,
                             int* __restrict__ cursor, unsigned* __restrict__ srcet){
  int e = blockIdx.x*blockDim.x + threadIdx.x;
  if (e >= E) return;
  int pos = atomicAdd(&cursor[ei[E + e]], 1);
  srcet[pos] = ((unsigned)ety[e] << 16) | (unsigned)ei[e];
}

// ---------------- QKV GEMM (MFMA): out Q bf16 [N,128], KV packed uint [N,128] (k lo | v hi) ----------------
__global__ __launch_bounds__(256) void gemm_qkv(const bf16* __restrict__ nfb, const bf16* __restrict__ qeb,
      const bf16* __restrict__ Wcat, const float* __restrict__ bcat,
      short* __restrict__ Qs, short* __restrict__ KVs, int M){
  constexpr int BK=32, LDT=40, K=256;
  __shared__ short As[64*LDT];
  __shared__ short Bs[64*LDT];
  const int tid  = threadIdx.x;
  const int lane = tid & 63;
  const int wave = tid >> 6;
  const int wm = (wave >> 1) * 32, wn = (wave & 1) * 32;
  const long m0 = (long)blockIdx.x * 64;
  const int  n0 = blockIdx.y * 64;
  floatx4 acc00 = {0.f,0.f,0.f,0.f}, acc01 = {0.f,0.f,0.f,0.f};
  floatx4 acc10 = {0.f,0.f,0.f,0.f}, acc11 = {0.f,0.f,0.f,0.f};
  const int srow = tid >> 2, scg = (tid & 3) * 8;
  const int r = lane & 15, q = lane >> 4;
  const short* Ag = (const short*)nfb;
  const short* Qg = (const short*)qeb;
  const short* Bg = (const short*)Wcat;
  for (int k0 = 0; k0 < K; k0 += BK){
    short8 va = {0,0,0,0,0,0,0,0};
    if (k0 < 128){
      long ar = m0 + srow;
      if (ar < M) va = *(const short8*)(Ag + ar*128 + k0 + scg);
    } else {
      va = *(const short8*)(Qg + (k0-128) + scg);   // row-independent broadcast
    }
    *(short8*)(&As[srow*LDT + scg]) = va;
    *(short8*)(&Bs[srow*LDT + scg]) = *(const short8*)(Bg + (long)(n0 + srow)*K + k0 + scg);
    __syncthreads();
    short8 a0 = *(const short8*)(&As[(wm      + r)*LDT + q*8]);
    short8 a1 = *(const short8*)(&As[(wm + 16 + r)*LDT + q*8]);
    short8 b0 = *(const short8*)(&Bs[(wn      + r)*LDT + q*8]);
    short8 b1 = *(const short8*)(&Bs[(wn + 16 + r)*LDT + q*8]);
    acc00 = __builtin_amdgcn_mfma_f32_16x16x32_bf16(a0, b0, acc00, 0, 0, 0);
    acc01 = __builtin_amdgcn_mfma_f32_16x16x32_bf16(a0, b1, acc01, 0, 0, 0);
    acc10 = __builtin_amdgcn_mfma_f32_16x16x32_bf16(a1, b0, acc10, 0, 0, 0);
    acc11 = __builtin_amdgcn_mfma_f32_16x16x32_bf16(a1, b1, acc11, 0, 0, 0);
    __syncthreads();
  }
  #pragma unroll
  for (int i=0;i<2;i++)
  #pragma unroll
  for (int j=0;j<2;j++){
    floatx4 av = (i==0) ? ((j==0)?acc00:acc01) : ((j==0)?acc10:acc11);
    int col = n0 + wn + j*16 + r;
    float bsv = bcat[col];
    #pragma unroll
    for (int g=0; g<4; g++){
      long row = m0 + wm + i*16 + q*4 + g;
      if (row < M){
        short bits = bfbits(av[g] + bsv);
        if (col < 128)      Qs[row*128 + col] = bits;
        else if (col < 256) KVs[row*256 + (col-128)*2]     = bits;  // k -> low half
        else                KVs[row*256 + (col-256)*2 + 1] = bits;  // v -> high half
      }
    }
  }
}

// ---------------- generic GEMM (MFMA, used for Wo): C f32 = A_bf16 @ B_bf16^T + bias ----------------
__global__ __launch_bounds__(256) void gemm_bt(const bf16* __restrict__ A, const bf16* __restrict__ B,
      const float* __restrict__ bias, float* __restrict__ C, int M, int N, int K){
  constexpr int BK=32, LDT=40;
  __shared__ short As[64*LDT];
  __shared__ short Bs[64*LDT];
  const int tid  = threadIdx.x;
  const int lane = tid & 63;
  const int wave = tid >> 6;
  const int wm = (wave >> 1) * 32, wn = (wave & 1) * 32;
  const long m0 = (long)blockIdx.x * 64;
  const int  n0 = blockIdx.y * 64;
  floatx4 acc00 = {0.f,0.f,0.f,0.f}, acc01 = {0.f,0.f,0.f,0.f};
  floatx4 acc10 = {0.f,0.f,0.f,0.f}, acc11 = {0.f,0.f,0.f,0.f};
  const int srow = tid >> 2, scg = (tid & 3) * 8;
  const int r = lane & 15, q = lane >> 4;
  const short* Ag = (const short*)A;
  const short* Bg = (const short*)B;
  for (int k0 = 0; k0 < K; k0 += BK){
    short8 va = {0,0,0,0,0,0,0,0};
    long ar = m0 + srow;
    if (ar < M) va = *(const short8*)(Ag + ar*K + k0 + scg);
    *(short8*)(&As[srow*LDT + scg]) = va;
    *(short8*)(&Bs[srow*LDT + scg]) = *(const short8*)(Bg + (long)(n0 + srow)*K + k0 + scg);
    __syncthreads();
    short8 a0 = *(const short8*)(&As[(wm      + r)*LDT + q*8]);
    short8 a1 = *(const short8*)(&As[(wm + 16 + r)*LDT + q*8]);
    short8 b0 = *(const short8*)(&Bs[(wn      + r)*LDT + q*8]);
    short8 b1 = *(const short8*)(&Bs[(wn + 16 + r)*LDT + q*8]);
    acc00 = __builtin_amdgcn_mfma_f32_16x16x32_bf16(a0, b0, acc00, 0, 0, 0);
    acc01 = __builtin_amdgcn_mfma_f32_16x16x32_bf16(a0, b1, acc01, 0, 0, 0);
    acc10 = __builtin_amdgcn_mfma_f32_16x16x32_bf16(a1, b0, acc10, 0, 0, 0);
    acc11 = __builtin_amdgcn_mfma_f32_16x16x32_bf16(a1, b1, acc11, 0, 0, 0);
    __syncthreads();
  }
  #pragma unroll
  for (int i=0;i<2;i++)
  #pragma unroll
  for (int j=0;j<2;j++){
    floatx4 av = (i==0) ? ((j==0)?acc00:acc01) : ((j==0)?acc10:acc11);
    int col = n0 + wn + j*16 + r;
    float bsv = bias[col];
    #pragma unroll
    for (int g=0; g<4; g++){
      long row = m0 + wm + i*16 + q*4 + g;
      if (row < M) C[row*(long)N + col] = av[g] + bsv;
    }
  }
}

// ---------------- single-pass attention: agg = (sum es*v) / (sum es + 1e-8) ----------------
__global__ __launch_bounds__(128) void attn_agg(const bf16* __restrict__ Q,
     const unsigned* __restrict__ KV, const bf16* __restrict__ relb,
     const int* __restrict__ rowptr, const unsigned* __restrict__ srcet,
     bf16* __restrict__ agg){
  int n = blockIdx.x, t = threadIdx.x;
  __shared__ unsigned ses[128];
  float qv = b2f(Q[(long)n*128 + t]);
  int beg = rowptr[n], end = rowptr[n+1];
  float denom = 0.f, acc = 0.f;
  for (int c = beg; c < end; c += 128){
    int cnt = end - c; if (cnt > 128) cnt = 128;
    __syncthreads();
    if (t < cnt) ses[t] = srcet[c + t];
    __syncthreads();
    for (int j = 0; j < cnt; ++j){
      unsigned se = ses[j];
      int src = se & 0xFFFF;
      int et  = se >> 16;
      unsigned kv = KV[(long)src*128 + t];
      float kb = lo2f(kv) + b2f(relb[et*128 + t]);
      float p = qv * kb;
      p += __shfl_xor(p, 1); p += __shfl_xor(p, 2);
      p += __shfl_xor(p, 4); p += __shfl_xor(p, 8);
      float es = __expf(p * 0.25f);
      denom += es;
      acc = fmaf(es, hi2f(kv), acc);
    }
  }
  agg[(long)n*128 + t] = f2b(acc / (denom + 1e-8f));
}

// ---------------- residual + LN1: x = LN(nf + attn), out bf16 ----------------
__global__ __launch_bounds__(128) void ln_add1(const float* __restrict__ nf, const float* __restrict__ attn,
     const float* __restrict__ g, const float* __restrict__ b, bf16* __restrict__ xout){
  long n = blockIdx.x; int t = threadIdx.x;
  float y = nf[n*128 + t] + attn[n*128 + t];
  float s = y, s2 = y*y;
  #pragma unroll
  for (int off=32; off>0; off>>=1){ s += __shfl_xor(s, off); s2 += __shfl_xor(s2, off); }
  __shared__ float ps[4];
  if ((t & 63) == 0){ ps[(t>>6)*2] = s; ps[(t>>6)*2+1] = s2; }
  __syncthreads();
  float tot = ps[0] + ps[2], tot2 = ps[1] + ps[3];
  float mu = tot * (1.f/128.f);
  float var = tot2 * (1.f/128.f) - mu*mu;
  float rs = rsqrtf(var + 1e-5f);
  xout[n*128 + t] = f2b((y - mu)*rs*g[t] + b[t]);
}

// ---------------- fused FFN (MFMA), h split in 2 halves -> 68.6 KB LDS -> 2 blocks/CU ----------------
__global__ __launch_bounds__(256) void ffn_fused(const bf16* __restrict__ X, const bf16* __restrict__ W1,
    const float* __restrict__ b1, const bf16* __restrict__ W2, const float* __restrict__ b2,
    float* __restrict__ Out, int M){
  __shared__ short Xs[64*136];
  __shared__ short Hs[64*264];
  __shared__ short Ws[64*136];
  const int tid = threadIdx.x, lane = tid & 63, wave = tid >> 6;
  const int r = lane & 15, q = lane >> 4;
  const int wm = (wave >> 1) * 32, wn = (wave & 1) * 32;
  const long m0 = (long)blockIdx.x * 64;
  const short* Xg  = (const short*)X;
  const short* W1g = (const short*)W1;
  const short* W2g = (const short*)W2;
  #pragma unroll
  for (int c=0;c<4;c++){
    int idx = c*256 + tid, row = idx >> 4, ch = (idx & 15) * 8;
    short8 v = {0,0,0,0,0,0,0,0};
    long ar = m0 + row;
    if (ar < M) v = *(const short8*)(Xg + ar*128 + ch);
    *(short8*)(&Xs[row*136 + ch]) = v;
  }
  const int wn2 = (wave & 1) * 64;
  floatx4 o[2][4];
  #pragma unroll
  for (int i=0;i<2;i++)
  #pragma unroll
  for (int j=0;j<4;j++) o[i][j] = (floatx4){0.f,0.f,0.f,0.f};
  for (int half = 0; half < 2; ++half){
    const int hb = half * 256;
    // phase 1: h[:, hb:hb+256] = gelu(x @ W1[hb:hb+256]^T + b1), into Hs
    for (int c0 = 0; c0 < 256; c0 += 64){
      #pragma unroll
      for (int c=0;c<4;c++){
        int idx = c*256 + tid, row = idx >> 4, ch = (idx & 15) * 8;
        *(short8*)(&Ws[row*136 + ch]) = *(const short8*)(W1g + (long)(hb + c0 + row)*128 + ch);
      }
      __syncthreads();
      floatx4 h00 = {0.f,0.f,0.f,0.f}, h01 = {0.f,0.f,0.f,0.f};
      floatx4 h10 = {0.f,0.f,0.f,0.f}, h11 = {0.f,0.f,0.f,0.f};
      #pragma unroll
      for (int k0 = 0; k0 < 128; k0 += 32){
        short8 a0 = *(const short8*)(&Xs[(wm      + r)*136 + k0 + q*8]);
        short8 a1 = *(const short8*)(&Xs[(wm + 16 + r)*136 + k0 + q*8]);
        short8 b0 = *(const short8*)(&Ws[(wn      + r)*136 + k0 + q*8]);
        short8 bv = *(const short8*)(&Ws[(wn + 16 + r)*136 + k0 + q*8]);
        h00 = __builtin_amdgcn_mfma_f32_16x16x32_bf16(a0, b0, h00, 0, 0, 0);
        h01 = __builtin_amdgcn_mfma_f32_16x16x32_bf16(a0, bv, h01, 0, 0, 0);
        h10 = __builtin_amdgcn_mfma_f32_16x16x32_bf16(a1, b0, h10, 0, 0, 0);
        h11 = __builtin_amdgcn_mfma_f32_16x16x32_bf16(a1, bv, h11, 0, 0, 0);
      }
      #pragma unroll
      for (int i=0;i<2;i++)
      #pragma unroll
      for (int j=0;j<2;j++){
        floatx4 av = (i==0) ? ((j==0)?h00:h01) : ((j==0)?h10:h11);
        int col = wn + j*16 + r;
        float bb = b1[hb + c0 + col];
        #pragma unroll
        for (int g=0; g<4; g++){
          int row = wm + i*16 + q*4 + g;
          float v = av[g] + bb;
          v = 0.5f * v * (1.f + erff(v * 0.70710678118f));   // exact GELU
          Hs[row*264 + c0 + col] = bfbits(v);
        }
      }
      __syncthreads();
    }
    // phase 2: partial out += h_half @ W2[:, hb:hb+256]^T
    for (int k0 = 0; k0 < 256; k0 += 32){
      #pragma unroll
      for (int c=0;c<2;c++){
        int idx = c*256 + tid, row = idx >> 2, ch = (idx & 3) * 8;
        *(short8*)(&Ws[row*40 + ch]) = *(const short8*)(W2g + (long)row*512 + hb + k0 + ch);
      }
      __syncthreads();
      short8 a0 = *(const short8*)(&Hs[(wm      + r)*264 + k0 + q*8]);
      short8 a1 = *(const short8*)(&Hs[(wm + 16 + r)*264 + k0 + q*8]);
      #pragma unroll
      for (int j=0;j<4;j++){
        short8 bj = *(const short8*)(&Ws[(wn2 + j*16 + r)*40 + q*8]);
        o[0][j] = __builtin_amdgcn_mfma_f32_16x16x32_bf16(a0, bj, o[0][j], 0, 0, 0);
        o[1][j] = __builtin_amdgcn_mfma_f32_16x16x32_bf16(a1, bj, o[1][j], 0, 0, 0);
      }
      __syncthreads();
    }
  }
  #pragma unroll
  for (int i=0;i<2;i++)
  #pragma unroll
  for (int j=0;j<4;j++){
    int col = wn2 + j*16 + r;
    float bb = b2[col];
    #pragma unroll
    for (int g=0; g<4; g++){
      long row = m0 + wm + i*16 + q*4 + g;
      if (row < M) Out[row*128 + col] = o[i][j][g] + bb;
    }
  }
}

// ---------------- residual + LN2: out = LN(x + ffo), f32 out ----------------
__global__ __launch_bounds__(128) void ln_add2(const bf16* __restrict__ X, const float* __restrict__ ffo,
     const float* __restrict__ g, const float* __restrict__ b, float* __restrict__ out){
  long n = blockIdx.x; int t = threadIdx.x;
  float y = b2f(X[n*128 + t]) + ffo[n*128 + t];
  float s = y, s2 = y*y;
  #pragma unroll
  for (int off=32; off>0; off>>=1){ s += __shfl_xor(s, off); s2 += __shfl_xor(s2, off); }
  __shared__ float ps[4];
  if ((t & 63) == 0){ ps[(t>>6)*2] = s; ps[(t>>6)*2+1] = s2; }
  __syncthreads();
  float tot = ps[0] + ps[2], tot2 = ps[1] + ps[3];
  float mu = tot * (1.f/128.f);
  float var = tot2 * (1.f/128.f) - mu*mu;
  float rs = rsqrtf(var + 1e-5f);
  out[n*128 + t] = (y - mu)*rs*g[t] + b[t];
}

// ---------------- relational interaction layer (R=100, naive f32) ----------------
__device__ __forceinline__ float dotf(const float* __restrict__ s, const float* __restrict__ w, int n){
  float acc = 0.f;
  const float4* w4 = (const float4*)w;
  #pragma unroll 4
  for (int j = 0; j < (n >> 2); ++j){
    float4 wv = w4[j];
    acc += s[4*j]*wv.x + s[4*j+1]*wv.y + s[4*j+2]*wv.z + s[4*j+3]*wv.w;
  }
  return acc;
}

__global__ __launch_bounds__(128) void rel_layer(const float* __restrict__ rel, const float* __restrict__ relW,
    const float* __restrict__ relb, const float* __restrict__ Wc, const float* __restrict__ bc,
    const float* __restrict__ gn, const float* __restrict__ bn, float* __restrict__ out){
  int rr = blockIdx.x, t = threadIdx.x;
  __shared__ float rrow[128];
  __shared__ float comb[512];
  rrow[t] = rel[(long)rr*128 + t];
  __syncthreads();
  #pragma unroll
  for (int k=0;k<4;k++){
    comb[k*128 + t] = dotf(rrow, relW + ((long)(k*128) + t)*128, 128) + relb[k*128 + t];
  }
  __syncthreads();
  float c2 = dotf(comb, Wc + (long)t*512, 512) + bc[t];
  float y = rrow[t] + c2;
  float s = y, s2 = y*y;
  #pragma unroll
  for (int off=32; off>0; off>>=1){ s += __shfl_xor(s, off); s2 += __shfl_xor(s2, off); }
  __shared__ float ps[4];
  if ((t & 63) == 0){ ps[(t>>6)*2] = s; ps[(t>>6)*2+1] = s2; }
  __syncthreads();
  float tot = ps[0] + ps[2], tot2 = ps[1] + ps[3];
  float mu = tot * (1.f/128.f);
  float var = tot2 * (1.f/128.f) - mu*mu;
  float rs = rsqrtf(var + 1e-5f);
  out[(long)rr*128 + t] = (y - mu)*rs*gn[t] + bn[t];
}

extern "C" void kernel_launch(void* const* d_in, const int* in_sizes, int n_in,
                              void* d_out, int out_size, void* d_ws, size_t ws_size,
                              hipStream_t stream){
  const int H = 128;
  auto S = [&](int i){ return in_sizes[i]; };
  bool ok = (n_in == 27);
  if (ok){
    ok = ok && S(1)==H && (S(0)%H)==0 && S(2)==2*S(3) && (S(4)%H)==0;
    ok = ok && S(5)==2*H*H && S(7)==2*H*H && S(9)==H*H && S(11)==H*H;
    ok = ok && S(17)==4*H*H && S(19)==4*H*H && S(21)==4*H*H && S(23)==4*H*H;
    ok = ok && out_size == S(0) + S(4);
  }
  if (!ok){
    fill_const<<<(out_size + 255)/256, 256, 0, stream>>>((float*)d_out, 100.0f, out_size);
    return;
  }

  const float* nf   = (const float*)d_in[0];
  const float* qe   = (const float*)d_in[1];
  const int*   ei   = (const int*)  d_in[2];
  const int*   ety  = (const int*)  d_in[3];
  const float* rel  = (const float*)d_in[4];
  const float* Wq   = (const float*)d_in[5];
  const float* bq   = (const float*)d_in[6];
  const float* Wk   = (const float*)d_in[7];
  const float* bk   = (const float*)d_in[8];
  const float* Wv   = (const float*)d_in[9];
  const float* bv   = (const float*)d_in[10];
  const float* Wo   = (const float*)d_in[11];
  const float* bo   = (const float*)d_in[12];
  const float* n1g  = (const float*)d_in[13];
  const float* n1b  = (const float*)d_in[14];
  const float* n2g  = (const float*)d_in[15];
  const float* n2b  = (const float*)d_in[16];
  const float* W1   = (const float*)d_in[17];
  const float* b1   = (const float*)d_in[18];
  const float* W2   = (const float*)d_in[19];
  const float* b2v  = (const float*)d_in[20];
  const float* relW = (const float*)d_in[21];
  const float* relbp= (const float*)d_in[22];
  const float* Wc   = (const float*)d_in[23];
  const float* bc   = (const float*)d_in[24];
  const float* rng  = (const float*)d_in[25];
  const float* rnb  = (const float*)d_in[26];

  const int N = in_sizes[0] / 128;
  const int E = in_sizes[2] / 2;
  const int R = in_sizes[4] / 128;

  char* ws = (char*)d_ws;
  size_t off = 0;
  auto alloc = [&](size_t bytes)->char*{
    char* p = ws + off; off = (off + bytes + 255) & ~(size_t)255; return p;
  };
  // regNA: nfb bf16 [N,128] -> aggp bf16 [N,128] (nfb dead after gemm_qkv)
  char*     regNA  = alloc((size_t)N * 256);
  // regKV: KV uint [N,128] -> attn f32 [N,128] -> ffo f32 [N,128]
  char*     regKV  = alloc((size_t)N * 512);
  bf16*     Qb     = (bf16*)    alloc((size_t)N * 256);   // dead after attn_agg
  bf16*     xlb    = (bf16*)    alloc((size_t)N * 256);
  bf16*     qeb    = (bf16*)    alloc(256);
  bf16*     Wcat   = (bf16*)    alloc((size_t)384*256*2);
  float*    bcat   = (float*)   alloc(384*4);
  bf16*     Wob    = (bf16*)    alloc((size_t)128*128*2);
  bf16*     W1b    = (bf16*)    alloc((size_t)512*128*2);
  bf16*     W2b    = (bf16*)    alloc((size_t)128*512*2);
  bf16*     relb16 = (bf16*)    alloc((size_t)R*128*2);
  int*      deg    = (int*)     alloc((size_t)N * 4);
  int*      rowptr = (int*)     alloc((size_t)(N+1) * 4);
  int*      cursor = (int*)     alloc((size_t)N * 4);
  unsigned* srcet  = (unsigned*)alloc((size_t)E * 4);

  if (off > ws_size){
    fill_const<<<(out_size + 255)/256, 256, 0, stream>>>((float*)d_out, 50.0f, out_size);
    return;
  }

  bf16*     nfb  = (bf16*)regNA;
  bf16*     aggp = (bf16*)regNA;     // overlays nfb
  unsigned* KV   = (unsigned*)regKV;
  float*    attn = (float*)regKV;    // overlays KV (dead after attn_agg)
  float*    ffo  = (float*)regKV;    // overlays attn (dead after ln_add1)
  float*    outx = (float*)d_out;
  float*    outr = (float*)d_out + (size_t)N*128;

  // conversions
  conv_f2b<<<(N*128 + 255)/256, 256, 0, stream>>>(nf, nfb, N*128);
  conv_f2b<<<1, 128, 0, stream>>>(qe, qeb, 128);
  build_wcat<<<(384*256 + 255)/256, 256, 0, stream>>>(Wq, Wk, Wv, bq, bk, bv, Wcat, bcat);
  conv_f2b<<<(128*128 + 255)/256, 256, 0, stream>>>(Wo, Wob, 128*128);
  conv_f2b<<<(512*128 + 255)/256, 256, 0, stream>>>(W1, W1b, 512*128);
  conv_f2b<<<(128*512 + 255)/256, 256, 0, stream>>>(W2, W2b, 128*512);
  conv_f2b<<<(R*128 + 255)/256, 256, 0, stream>>>(relbp - 0 + 0 == nullptr ? relbp : rel, relb16, R*128);

  // CSR
  hipMemsetAsync(deg, 0, (size_t)N*4, stream);
  edge_hist<<<(E + 255)/256, 256, 0, stream>>>(ei, E, deg);
  scan_kernel<<<1, 1024, 0, stream>>>(deg, rowptr, cursor, N, E);
  edge_scatter<<<(E + 255)/256, 256, 0, stream>>>(ei, ety, E, cursor, srcet);

  // pipeline
  dim3 g1((N + 63)/64, 6);
  gemm_qkv<<<g1, 256, 0, stream>>>(nfb, qeb, Wcat, bcat, (short*)Qb, (short*)KV, N);
  attn_agg<<<N, 128, 0, stream>>>(Qb, KV, relb16, rowptr, srcet, aggp);
  dim3 g2((N + 63)/64, 2);
  gemm_bt<<<g2, 256, 0, stream>>>(aggp, Wob, bo, attn, N, 128, 128);
  ln_add1<<<N, 128, 0, stream>>>(nf, attn, n1g, n1b, xlb);
  ffn_fused<<<(N + 63)/64, 256, 0, stream>>>(xlb, W1b, b1, W2b, b2v, ffo, N);
  ln_add2<<<N, 128, 0, stream>>>(xlb, ffo, n2g, n2b, outx);
  rel_layer<<<R, 128, 0, stream>>>(rel, relW, relbp, Wc, bc, rng, rnb, outr);
}

// Round 12
// 591.499 us; speedup vs baseline: 9.0234x; 1.0699x over previous
//
#include <hip/hip_runtime.h>
#include <hip/hip_bf16.h>
#include <math.h>

using bf16 = __hip_bfloat16;
typedef _Float16 hf;
typedef hf __attribute__((ext_vector_type(2))) hf2;
typedef __attribute__((ext_vector_type(8))) short short8;
typedef __attribute__((ext_vector_type(4))) float floatx4;

__device__ __forceinline__ float b2f(bf16 x){ return __bfloat162float(x); }
__device__ __forceinline__ bf16 f2b(float x){ return __float2bfloat16(x); }
__device__ __forceinline__ short bfbits(float x){ bf16 t = __float2bfloat16(x); return *(short*)&t; }
__device__ __forceinline__ short hfbits(float x){ hf t = (hf)x; return *(short*)&t; }
__device__ __forceinline__ hf2 u2h2(unsigned u){ return *(hf2*)&u; }

__global__ void fill_const(float* __restrict__ p, float v, int n){
  int i = blockIdx.x*blockDim.x + threadIdx.x;
  if (i < n) p[i] = v;
}

__global__ void conv_f2b(const float* __restrict__ src, bf16* __restrict__ dst, int n){
  int i = blockIdx.x*blockDim.x + threadIdx.x;
  if (i < n) dst[i] = f2b(src[i]);
}

__global__ void conv_f2h(const float* __restrict__ src, short* __restrict__ dst, int n){
  int i = blockIdx.x*blockDim.x + threadIdx.x;
  if (i < n) dst[i] = hfbits(src[i]);
}

// Wcat bf16 [384,256] = [Wq; Wk; Wv|0], bcat f32 [384]
__global__ void build_wcat(const float* __restrict__ Wq, const float* __restrict__ Wk,
                           const float* __restrict__ Wv, const float* __restrict__ bq,
                           const float* __restrict__ bk, const float* __restrict__ bv,
                           bf16* __restrict__ Wcat, float* __restrict__ bcat){
  int i = blockIdx.x*blockDim.x + threadIdx.x;
  if (i >= 384*256) return;
  int r = i >> 8, c = i & 255;
  float v;
  if (r < 128)       v = Wq[r*256 + c];
  else if (r < 256)  v = Wk[(r-128)*256 + c];
  else               v = (c < 128) ? Wv[(r-256)*128 + c] : 0.f;
  Wcat[i] = f2b(v);
  if (i < 384) bcat[i] = (i < 128) ? bq[i] : (i < 256 ? bk[i-128] : bv[i-256]);
}

// ---------------- CSR build ----------------
__global__ void edge_hist(const int* __restrict__ ei, int E, int* __restrict__ deg){
  int e = blockIdx.x*blockDim.x + threadIdx.x;
  if (e >= E) return;
  atomicAdd(&deg[ei[E + e]], 1);
}

__global__ __launch_bounds__(1024) void scan_kernel(const int* __restrict__ deg,
      int* __restrict__ rowptr, int* __restrict__ cursor, int Nn, int E){
  __shared__ int sums[1024];
  int t = threadIdx.x;
  int chunk = (Nn + 1023) >> 10;
  int b0 = t*chunk;
  int s = 0;
  for (int i=0;i<chunk;i++){ int idx=b0+i; if (idx<Nn) s += deg[idx]; }
  sums[t] = s;
  __syncthreads();
  for (int off=1; off<1024; off<<=1){
    int v = (t>=off) ? sums[t-off] : 0;
    __syncthreads();
    sums[t] += v;
    __syncthreads();
  }
  int run = (t==0) ? 0 : sums[t-1];
  for (int i=0;i<chunk;i++){
    int idx=b0+i;
    if (idx<Nn){ rowptr[idx]=run; cursor[idx]=run; run += deg[idx]; }
  }
  if (t==1023) rowptr[Nn] = E;
}

__global__ void edge_scatter(const int* __restrict__ ei, const int* __restrict__ ety, int E,
                             int* __restrict__ cursor, unsigned* __restrict__ srcet){
  int e = blockIdx.x*blockDim.x + threadIdx.x;
  if (e >= E) return;
  int pos = atomicAdd(&cursor[ei[E + e]], 1);
  srcet[pos] = ((unsigned)ety[e] << 16) | (unsigned)ei[e];
}

// ---------------- QKV GEMM (MFMA): Q f16 [N,128]; KV packed [N,64] lanes of [k0,k1,v0,v1] f16 ----------------
__global__ __launch_bounds__(256) void gemm_qkv(const bf16* __restrict__ nfb, const bf16* __restrict__ qeb,
      const bf16* __restrict__ Wcat, const float* __restrict__ bcat,
      short* __restrict__ Qs, short* __restrict__ KVs, int M){
  constexpr int BK=32, LDT=40, K=256;
  __shared__ short As[64*LDT];
  __shared__ short Bs[64*LDT];
  const int tid  = threadIdx.x;
  const int lane = tid & 63;
  const int wave = tid >> 6;
  const int wm = (wave >> 1) * 32, wn = (wave & 1) * 32;
  const long m0 = (long)blockIdx.x * 64;
  const int  n0 = blockIdx.y * 64;
  floatx4 acc00 = {0.f,0.f,0.f,0.f}, acc01 = {0.f,0.f,0.f,0.f};
  floatx4 acc10 = {0.f,0.f,0.f,0.f}, acc11 = {0.f,0.f,0.f,0.f};
  const int srow = tid >> 2, scg = (tid & 3) * 8;
  const int r = lane & 15, q = lane >> 4;
  const short* Ag = (const short*)nfb;
  const short* Qg = (const short*)qeb;
  const short* Bg = (const short*)Wcat;
  for (int k0 = 0; k0 < K; k0 += BK){
    short8 va = {0,0,0,0,0,0,0,0};
    if (k0 < 128){
      long ar = m0 + srow;
      if (ar < M) va = *(const short8*)(Ag + ar*128 + k0 + scg);
    } else {
      va = *(const short8*)(Qg + (k0-128) + scg);   // row-independent broadcast
    }
    *(short8*)(&As[srow*LDT + scg]) = va;
    *(short8*)(&Bs[srow*LDT + scg]) = *(const short8*)(Bg + (long)(n0 + srow)*K + k0 + scg);
    __syncthreads();
    short8 a0 = *(const short8*)(&As[(wm      + r)*LDT + q*8]);
    short8 a1 = *(const short8*)(&As[(wm + 16 + r)*LDT + q*8]);
    short8 b0 = *(const short8*)(&Bs[(wn      + r)*LDT + q*8]);
    short8 b1 = *(const short8*)(&Bs[(wn + 16 + r)*LDT + q*8]);
    acc00 = __builtin_amdgcn_mfma_f32_16x16x32_bf16(a0, b0, acc00, 0, 0, 0);
    acc01 = __builtin_amdgcn_mfma_f32_16x16x32_bf16(a0, b1, acc01, 0, 0, 0);
    acc10 = __builtin_amdgcn_mfma_f32_16x16x32_bf16(a1, b0, acc10, 0, 0, 0);
    acc11 = __builtin_amdgcn_mfma_f32_16x16x32_bf16(a1, b1, acc11, 0, 0, 0);
    __syncthreads();
  }
  #pragma unroll
  for (int i=0;i<2;i++)
  #pragma unroll
  for (int j=0;j<2;j++){
    floatx4 av = (i==0) ? ((j==0)?acc00:acc01) : ((j==0)?acc10:acc11);
    int col = n0 + wn + j*16 + r;
    float bsv = bcat[col];
    #pragma unroll
    for (int g=0; g<4; g++){
      long row = m0 + wm + i*16 + q*4 + g;
      if (row < M){
        short bits = hfbits(av[g] + bsv);
        if (col < 128)      Qs[row*128 + col] = bits;
        else if (col < 256){ int d = col - 128; KVs[row*256 + ((d>>1)<<2) + (d&1)] = bits; }
        else               { int d = col - 256; KVs[row*256 + ((d>>1)<<2) + 2 + (d&1)] = bits; }
      }
    }
  }
}

// ---------------- generic GEMM (MFMA, used for Wo): C f32 = A_bf16 @ B_bf16^T + bias ----------------
__global__ __launch_bounds__(256) void gemm_bt(const bf16* __restrict__ A, const bf16* __restrict__ B,
      const float* __restrict__ bias, float* __restrict__ C, int M, int N, int K){
  constexpr int BK=32, LDT=40;
  __shared__ short As[64*LDT];
  __shared__ short Bs[64*LDT];
  const int tid  = threadIdx.x;
  const int lane = tid & 63;
  const int wave = tid >> 6;
  const int wm = (wave >> 1) * 32, wn = (wave & 1) * 32;
  const long m0 = (long)blockIdx.x * 64;
  const int  n0 = blockIdx.y * 64;
  floatx4 acc00 = {0.f,0.f,0.f,0.f}, acc01 = {0.f,0.f,0.f,0.f};
  floatx4 acc10 = {0.f,0.f,0.f,0.f}, acc11 = {0.f,0.f,0.f,0.f};
  const int srow = tid >> 2, scg = (tid & 3) * 8;
  const int r = lane & 15, q = lane >> 4;
  const short* Ag = (const short*)A;
  const short* Bg = (const short*)B;
  for (int k0 = 0; k0 < K; k0 += BK){
    short8 va = {0,0,0,0,0,0,0,0};
    long ar = m0 + srow;
    if (ar < M) va = *(const short8*)(Ag + ar*K + k0 + scg);
    *(short8*)(&As[srow*LDT + scg]) = va;
    *(short8*)(&Bs[srow*LDT + scg]) = *(const short8*)(Bg + (long)(n0 + srow)*K + k0 + scg);
    __syncthreads();
    short8 a0 = *(const short8*)(&As[(wm      + r)*LDT + q*8]);
    short8 a1 = *(const short8*)(&As[(wm + 16 + r)*LDT + q*8]);
    short8 b0 = *(const short8*)(&Bs[(wn      + r)*LDT + q*8]);
    short8 b1 = *(const short8*)(&Bs[(wn + 16 + r)*LDT + q*8]);
    acc00 = __builtin_amdgcn_mfma_f32_16x16x32_bf16(a0, b0, acc00, 0, 0, 0);
    acc01 = __builtin_amdgcn_mfma_f32_16x16x32_bf16(a0, b1, acc01, 0, 0, 0);
    acc10 = __builtin_amdgcn_mfma_f32_16x16x32_bf16(a1, b0, acc10, 0, 0, 0);
    acc11 = __builtin_amdgcn_mfma_f32_16x16x32_bf16(a1, b1, acc11, 0, 0, 0);
    __syncthreads();
  }
  #pragma unroll
  for (int i=0;i<2;i++)
  #pragma unroll
  for (int j=0;j<2;j++){
    floatx4 av = (i==0) ? ((j==0)?acc00:acc01) : ((j==0)?acc10:acc11);
    int col = n0 + wn + j*16 + r;
    float bsv = bias[col];
    #pragma unroll
    for (int g=0; g<4; g++){
      long row = m0 + wm + i*16 + q*4 + g;
      if (row < M) C[row*(long)N + col] = av[g] + bsv;
    }
  }
}

// ---------------- attention: 1 wave per node, lane owns dims {2l,2l+1} as f16 pairs ----------------
__global__ __launch_bounds__(256) void attn_agg(const unsigned* __restrict__ Qh,
     const uint2* __restrict__ KVh, const unsigned* __restrict__ Rh,
     const int* __restrict__ rowptr, const unsigned* __restrict__ srcet,
     unsigned* __restrict__ agg, int Nn){
  const int w = threadIdx.x >> 6, l = threadIdx.x & 63;
  const int n = blockIdx.x*4 + w;
  if (n >= Nn) return;
  hf2 q2 = u2h2(Qh[(long)n*64 + l]);
  int beg = rowptr[n], end = rowptr[n+1];
  float acc0 = 0.f, acc1 = 0.f, denom = 0.f;
  for (int c = beg; c < end; c += 64){
    int cnt = end - c; if (cnt > 64) cnt = 64;
    unsigned se_l = (c + l < end) ? srcet[c + l] : 0u;
    for (int j = 0; j < cnt; ++j){
      unsigned se = __shfl(se_l, j);
      int src = se & 0xFFFF;
      int et  = se >> 16;
      uint2 kv = KVh[(long)src*64 + l];
      hf2 kb = u2h2(kv.x) + u2h2(Rh[et*64 + l]);     // v_pk_add_f16
#if __has_builtin(__builtin_amdgcn_fdot2)
      float p = __builtin_amdgcn_fdot2(q2, kb, 0.f, false);
#else
      float p = fmaf((float)q2.y, (float)kb.y, (float)q2.x * (float)kb.x);
#endif
      p += __shfl_xor(p, 1); p += __shfl_xor(p, 2); p += __shfl_xor(p, 4);
      float es = __expf(p * 0.25f);
      denom += es;
      hf2 v2 = u2h2(kv.y);
      acc0 = fmaf(es, (float)v2.x, acc0);
      acc1 = fmaf(es, (float)v2.y, acc1);
    }
  }
  float inv = 1.f / (denom + 1e-8f);
  unsigned out = ((unsigned)(unsigned short)bfbits(acc1 * inv) << 16)
               |  (unsigned)(unsigned short)bfbits(acc0 * inv);
  agg[(long)n*64 + l] = out;
}

// ---------------- residual + LN1: x = LN(nf + attn), out bf16 ----------------
__global__ __launch_bounds__(128) void ln_add1(const float* __restrict__ nf, const float* __restrict__ attn,
     const float* __restrict__ g, const float* __restrict__ b, bf16* __restrict__ xout){
  long n = blockIdx.x; int t = threadIdx.x;
  float y = nf[n*128 + t] + attn[n*128 + t];
  float s = y, s2 = y*y;
  #pragma unroll
  for (int off=32; off>0; off>>=1){ s += __shfl_xor(s, off); s2 += __shfl_xor(s2, off); }
  __shared__ float ps[4];
  if ((t & 63) == 0){ ps[(t>>6)*2] = s; ps[(t>>6)*2+1] = s2; }
  __syncthreads();
  float tot = ps[0] + ps[2], tot2 = ps[1] + ps[3];
  float mu = tot * (1.f/128.f);
  float var = tot2 * (1.f/128.f) - mu*mu;
  float rs = rsqrtf(var + 1e-5f);
  xout[n*128 + t] = f2b((y - mu)*rs*g[t] + b[t]);
}

// ---------------- fused FFN (MFMA), h split in 2 halves -> 68.6 KB LDS -> 2 blocks/CU ----------------
__global__ __launch_bounds__(256) void ffn_fused(const bf16* __restrict__ X, const bf16* __restrict__ W1,
    const float* __restrict__ b1, const bf16* __restrict__ W2, const float* __restrict__ b2,
    float* __restrict__ Out, int M){
  __shared__ short Xs[64*136];
  __shared__ short Hs[64*264];
  __shared__ short Ws[64*136];
  const int tid = threadIdx.x, lane = tid & 63, wave = tid >> 6;
  const int r = lane & 15, q = lane >> 4;
  const int wm = (wave >> 1) * 32, wn = (wave & 1) * 32;
  const long m0 = (long)blockIdx.x * 64;
  const short* Xg  = (const short*)X;
  const short* W1g = (const short*)W1;
  const short* W2g = (const short*)W2;
  #pragma unroll
  for (int c=0;c<4;c++){
    int idx = c*256 + tid, row = idx >> 4, ch = (idx & 15) * 8;
    short8 v = {0,0,0,0,0,0,0,0};
    long ar = m0 + row;
    if (ar < M) v = *(const short8*)(Xg + ar*128 + ch);
    *(short8*)(&Xs[row*136 + ch]) = v;
  }
  const int wn2 = (wave & 1) * 64;
  floatx4 o[2][4];
  #pragma unroll
  for (int i=0;i<2;i++)
  #pragma unroll
  for (int j=0;j<4;j++) o[i][j] = (floatx4){0.f,0.f,0.f,0.f};
  for (int half = 0; half < 2; ++half){
    const int hb = half * 256;
    for (int c0 = 0; c0 < 256; c0 += 64){
      #pragma unroll
      for (int c=0;c<4;c++){
        int idx = c*256 + tid, row = idx >> 4, ch = (idx & 15) * 8;
        *(short8*)(&Ws[row*136 + ch]) = *(const short8*)(W1g + (long)(hb + c0 + row)*128 + ch);
      }
      __syncthreads();
      floatx4 h00 = {0.f,0.f,0.f,0.f}, h01 = {0.f,0.f,0.f,0.f};
      floatx4 h10 = {0.f,0.f,0.f,0.f}, h11 = {0.f,0.f,0.f,0.f};
      #pragma unroll
      for (int k0 = 0; k0 < 128; k0 += 32){
        short8 a0 = *(const short8*)(&Xs[(wm      + r)*136 + k0 + q*8]);
        short8 a1 = *(const short8*)(&Xs[(wm + 16 + r)*136 + k0 + q*8]);
        short8 b0 = *(const short8*)(&Ws[(wn      + r)*136 + k0 + q*8]);
        short8 bv = *(const short8*)(&Ws[(wn + 16 + r)*136 + k0 + q*8]);
        h00 = __builtin_amdgcn_mfma_f32_16x16x32_bf16(a0, b0, h00, 0, 0, 0);
        h01 = __builtin_amdgcn_mfma_f32_16x16x32_bf16(a0, bv, h01, 0, 0, 0);
        h10 = __builtin_amdgcn_mfma_f32_16x16x32_bf16(a1, b0, h10, 0, 0, 0);
        h11 = __builtin_amdgcn_mfma_f32_16x16x32_bf16(a1, bv, h11, 0, 0, 0);
      }
      #pragma unroll
      for (int i=0;i<2;i++)
      #pragma unroll
      for (int j=0;j<2;j++){
        floatx4 av = (i==0) ? ((j==0)?h00:h01) : ((j==0)?h10:h11);
        int col = wn + j*16 + r;
        float bb = b1[hb + c0 + col];
        #pragma unroll
        for (int g=0; g<4; g++){
          int row = wm + i*16 + q*4 + g;
          float v = av[g] + bb;
          v = 0.5f * v * (1.f + erff(v * 0.70710678118f));   // exact GELU
          Hs[row*264 + c0 + col] = bfbits(v);
        }
      }
      __syncthreads();
    }
    for (int k0 = 0; k0 < 256; k0 += 32){
      #pragma unroll
      for (int c=0;c<2;c++){
        int idx = c*256 + tid, row = idx >> 2, ch = (idx & 3) * 8;
        *(short8*)(&Ws[row*40 + ch]) = *(const short8*)(W2g + (long)row*512 + hb + k0 + ch);
      }
      __syncthreads();
      short8 a0 = *(const short8*)(&Hs[(wm      + r)*264 + k0 + q*8]);
      short8 a1 = *(const short8*)(&Hs[(wm + 16 + r)*264 + k0 + q*8]);
      #pragma unroll
      for (int j=0;j<4;j++){
        short8 bj = *(const short8*)(&Ws[(wn2 + j*16 + r)*40 + q*8]);
        o[0][j] = __builtin_amdgcn_mfma_f32_16x16x32_bf16(a0, bj, o[0][j], 0, 0, 0);
        o[1][j] = __builtin_amdgcn_mfma_f32_16x16x32_bf16(a1, bj, o[1][j], 0, 0, 0);
      }
      __syncthreads();
    }
  }
  #pragma unroll
  for (int i=0;i<2;i++)
  #pragma unroll
  for (int j=0;j<4;j++){
    int col = wn2 + j*16 + r;
    float bb = b2[col];
    #pragma unroll
    for (int g=0; g<4; g++){
      long row = m0 + wm + i*16 + q*4 + g;
      if (row < M) Out[row*128 + col] = o[i][j][g] + bb;
    }
  }
}

// ---------------- residual + LN2: out = LN(x + ffo), f32 out ----------------
__global__ __launch_bounds__(128) void ln_add2(const bf16* __restrict__ X, const float* __restrict__ ffo,
     const float* __restrict__ g, const float* __restrict__ b, float* __restrict__ out){
  long n = blockIdx.x; int t = threadIdx.x;
  float y = b2f(X[n*128 + t]) + ffo[n*128 + t];
  float s = y, s2 = y*y;
  #pragma unroll
  for (int off=32; off>0; off>>=1){ s += __shfl_xor(s, off); s2 += __shfl_xor(s2, off); }
  __shared__ float ps[4];
  if ((t & 63) == 0){ ps[(t>>6)*2] = s; ps[(t>>6)*2+1] = s2; }
  __syncthreads();
  float tot = ps[0] + ps[2], tot2 = ps[1] + ps[3];
  float mu = tot * (1.f/128.f);
  float var = tot2 * (1.f/128.f) - mu*mu;
  float rs = rsqrtf(var + 1e-5f);
  out[n*128 + t] = (y - mu)*rs*g[t] + b[t];
}

// ---------------- relational interaction layer (R=100, naive f32) ----------------
__device__ __forceinline__ float dotf(const float* __restrict__ s, const float* __restrict__ w, int n){
  float acc = 0.f;
  const float4* w4 = (const float4*)w;
  #pragma unroll 4
  for (int j = 0; j < (n >> 2); ++j){
    float4 wv = w4[j];
    acc += s[4*j]*wv.x + s[4*j+1]*wv.y + s[4*j+2]*wv.z + s[4*j+3]*wv.w;
  }
  return acc;
}

__global__ __launch_bounds__(128) void rel_layer(const float* __restrict__ rel, const float* __restrict__ relW,
    const float* __restrict__ relb, const float* __restrict__ Wc, const float* __restrict__ bc,
    const float* __restrict__ gn, const float* __restrict__ bn, float* __restrict__ out){
  int rr = blockIdx.x, t = threadIdx.x;
  __shared__ float rrow[128];
  __shared__ float comb[512];
  rrow[t] = rel[(long)rr*128 + t];
  __syncthreads();
  #pragma unroll
  for (int k=0;k<4;k++){
    comb[k*128 + t] = dotf(rrow, relW + ((long)(k*128) + t)*128, 128) + relb[k*128 + t];
  }
  __syncthreads();
  float c2 = dotf(comb, Wc + (long)t*512, 512) + bc[t];
  float y = rrow[t] + c2;
  float s = y, s2 = y*y;
  #pragma unroll
  for (int off=32; off>0; off>>=1){ s += __shfl_xor(s, off); s2 += __shfl_xor(s2, off); }
  __shared__ float ps[4];
  if ((t & 63) == 0){ ps[(t>>6)*2] = s; ps[(t>>6)*2+1] = s2; }
  __syncthreads();
  float tot = ps[0] + ps[2], tot2 = ps[1] + ps[3];
  float mu = tot * (1.f/128.f);
  float var = tot2 * (1.f/128.f) - mu*mu;
  float rs = rsqrtf(var + 1e-5f);
  out[(long)rr*128 + t] = (y - mu)*rs*gn[t] + bn[t];
}

extern "C" void kernel_launch(void* const* d_in, const int* in_sizes, int n_in,
                              void* d_out, int out_size, void* d_ws, size_t ws_size,
                              hipStream_t stream){
  const int H = 128;
  auto S = [&](int i){ return in_sizes[i]; };
  bool ok = (n_in == 27);
  if (ok){
    ok = ok && S(1)==H && (S(0)%H)==0 && S(2)==2*S(3) && (S(4)%H)==0;
    ok = ok && S(5)==2*H*H && S(7)==2*H*H && S(9)==H*H && S(11)==H*H;
    ok = ok && S(17)==4*H*H && S(19)==4*H*H && S(21)==4*H*H && S(23)==4*H*H;
    ok = ok && out_size == S(0) + S(4);
  }
  if (!ok){
    fill_const<<<(out_size + 255)/256, 256, 0, stream>>>((float*)d_out, 100.0f, out_size);
    return;
  }

  const float* nf   = (const float*)d_in[0];
  const float* qe   = (const float*)d_in[1];
  const int*   ei   = (const int*)  d_in[2];
  const int*   ety  = (const int*)  d_in[3];
  const float* rel  = (const float*)d_in[4];
  const float* Wq   = (const float*)d_in[5];
  const float* bq   = (const float*)d_in[6];
  const float* Wk   = (const float*)d_in[7];
  const float* bk   = (const float*)d_in[8];
  const float* Wv   = (const float*)d_in[9];
  const float* bv   = (const float*)d_in[10];
  const float* Wo   = (const float*)d_in[11];
  const float* bo   = (const float*)d_in[12];
  const float* n1g  = (const float*)d_in[13];
  const float* n1b  = (const float*)d_in[14];
  const float* n2g  = (const float*)d_in[15];
  const float* n2b  = (const float*)d_in[16];
  const float* W1   = (const float*)d_in[17];
  const float* b1   = (const float*)d_in[18];
  const float* W2   = (const float*)d_in[19];
  const float* b2v  = (const float*)d_in[20];
  const float* relW = (const float*)d_in[21];
  const float* relbp= (const float*)d_in[22];
  const float* Wc   = (const float*)d_in[23];
  const float* bc   = (const float*)d_in[24];
  const float* rng  = (const float*)d_in[25];
  const float* rnb  = (const float*)d_in[26];

  const int N = in_sizes[0] / 128;
  const int E = in_sizes[2] / 2;
  const int R = in_sizes[4] / 128;

  char* ws = (char*)d_ws;
  size_t off = 0;
  auto alloc = [&](size_t bytes)->char*{
    char* p = ws + off; off = (off + bytes + 255) & ~(size_t)255; return p;
  };
  // regNA: nfb bf16 [N,128] -> aggp bf16 [N,128] (nfb dead after gemm_qkv)
  char*     regNA  = alloc((size_t)N * 256);
  // regKV: KVh uint2 [N,64] -> attn f32 [N,128] -> ffo f32 [N,128]
  char*     regKV  = alloc((size_t)N * 512);
  unsigned* Qh     = (unsigned*)alloc((size_t)N * 256);   // f16 pairs; dead after attn_agg
  bf16*     xlb    = (bf16*)    alloc((size_t)N * 256);
  bf16*     qeb    = (bf16*)    alloc(256);
  bf16*     Wcat   = (bf16*)    alloc((size_t)384*256*2);
  float*    bcat   = (float*)   alloc(384*4);
  bf16*     Wob    = (bf16*)    alloc((size_t)128*128*2);
  bf16*     W1b    = (bf16*)    alloc((size_t)512*128*2);
  bf16*     W2b    = (bf16*)    alloc((size_t)128*512*2);
  short*    Rh     = (short*)   alloc((size_t)R*128*2);   // rel embeddings f16
  int*      deg    = (int*)     alloc((size_t)N * 4);
  int*      rowptr = (int*)     alloc((size_t)(N+1) * 4);
  int*      cursor = (int*)     alloc((size_t)N * 4);
  unsigned* srcet  = (unsigned*)alloc((size_t)E * 4);

  if (off > ws_size){
    fill_const<<<(out_size + 255)/256, 256, 0, stream>>>((float*)d_out, 50.0f, out_size);
    return;
  }

  bf16*     nfb  = (bf16*)regNA;
  unsigned* aggp = (unsigned*)regNA;  // bf16 pairs, overlays nfb
  uint2*    KVh  = (uint2*)regKV;
  float*    attn = (float*)regKV;     // overlays KVh (dead after attn_agg)
  float*    ffo  = (float*)regKV;     // overlays attn (dead after ln_add1)
  float*    outx = (float*)d_out;
  float*    outr = (float*)d_out + (size_t)N*128;

  // conversions
  conv_f2b<<<(N*128 + 255)/256, 256, 0, stream>>>(nf, nfb, N*128);
  conv_f2b<<<1, 128, 0, stream>>>(qe, qeb, 128);
  build_wcat<<<(384*256 + 255)/256, 256, 0, stream>>>(Wq, Wk, Wv, bq, bk, bv, Wcat, bcat);
  conv_f2b<<<(128*128 + 255)/256, 256, 0, stream>>>(Wo, Wob, 128*128);
  conv_f2b<<<(512*128 + 255)/256, 256, 0, stream>>>(W1, W1b, 512*128);
  conv_f2b<<<(128*512 + 255)/256, 256, 0, stream>>>(W2, W2b, 128*512);
  conv_f2h<<<(R*128 + 255)/256, 256, 0, stream>>>(rel, Rh, R*128);

  // CSR
  hipMemsetAsync(deg, 0, (size_t)N*4, stream);
  edge_hist<<<(E + 255)/256, 256, 0, stream>>>(ei, E, deg);
  scan_kernel<<<1, 1024, 0, stream>>>(deg, rowptr, cursor, N, E);
  edge_scatter<<<(E + 255)/256, 256, 0, stream>>>(ei, ety, E, cursor, srcet);

  // pipeline
  dim3 g1((N + 63)/64, 6);
  gemm_qkv<<<g1, 256, 0, stream>>>(nfb, qeb, Wcat, bcat, (short*)Qh, (short*)KVh, N);
  attn_agg<<<(N + 3)/4, 256, 0, stream>>>(Qh, KVh, (const unsigned*)Rh, rowptr, srcet, aggp, N);
  dim3 g2((N + 63)/64, 2);
  gemm_bt<<<g2, 256, 0, stream>>>((const bf16*)aggp, Wob, bo, attn, N, 128, 128);
  ln_add1<<<N, 128, 0, stream>>>(nf, attn, n1g, n1b, xlb);
  ffn_fused<<<(N + 63)/64, 256, 0, stream>>>(xlb, W1b, b1, W2b, b2v, ffo, N);
  ln_add2<<<N, 128, 0, stream>>>(xlb, ffo, n2g, n2b, outx);
  rel_layer<<<R, 128, 0, stream>>>(rel, relW, relbp, Wc, bc, rng, rnb, outr);
}